// Round 12
// baseline (217.598 us; speedup 1.0000x reference)
//
#include <hip/hip_runtime.h>
#include <stdint.h>

#define H 32
#define HKV 8
#define D 128
#define SQ 1024
#define CTX 3072
#define SKV 4096
#define FP8_MAX_C 448.0f
#define EPS_C 1e-8f

typedef __attribute__((ext_vector_type(4))) float f32x4;
typedef __attribute__((ext_vector_type(8))) __bf16 bf16x8;
typedef __attribute__((ext_vector_type(8))) unsigned short u16x8;

__device__ __forceinline__ unsigned short f2bf(float x) {
  unsigned int u = __builtin_bit_cast(unsigned int, x);
  u += 0x7fffu + ((u >> 16) & 1u);
  return (unsigned short)(u >> 16);
}

__device__ __forceinline__ f32x4 mfma16(bf16x8 a, bf16x8 b, f32x4 c) {
  return __builtin_amdgcn_mfma_f32_16x16x32_bf16(a, b, c, 0, 0, 0);
}

// async global->LDS, 16B per lane; dest = wave-uniform base + lane*16
__device__ __forceinline__ void gld16(const unsigned short* g, char* l) {
  __builtin_amdgcn_global_load_lds(
      (const __attribute__((address_space(1))) unsigned int*)g,
      (__attribute__((address_space(3))) unsigned int*)l, 16, 0, 0);
}

// explicit DMA drain before barrier (fixes replay-only race, R6/R7)
__device__ __forceinline__ void stage_sync() {
  asm volatile("s_waitcnt vmcnt(0)" ::: "memory");
  __builtin_amdgcn_sched_barrier(0);
  __syncthreads();
}

// ---- scales stage 1: partial absmax -> atomicMax on float bits ----
__global__ void scales_part(const float* __restrict__ k,
                            const float* __restrict__ v,
                            unsigned int* __restrict__ smax) {
  const int b = blockIdx.x & 15;
  const int part = blockIdx.x >> 4;
  const float* src = (b < HKV) ? k : v;
  const int h = b & 7;
  const int tid = threadIdx.x;
  const int d0 = (tid & 31) * 4;
  float mx = 0.f;
  const int t1 = part * 128 + 128;
  for (int t = part * 128 + (tid >> 5); t < t1; t += 8) {
    float4 vv = *reinterpret_cast<const float4*>(src + (size_t)t * (HKV * D) + h * D + d0);
    mx = fmaxf(mx, fmaxf(fmaxf(fabsf(vv.x), fabsf(vv.y)),
                         fmaxf(fabsf(vv.z), fabsf(vv.w))));
  }
  __shared__ float red[256];
  red[tid] = mx;
  __syncthreads();
  for (int s = 128; s > 0; s >>= 1) {
    if (tid < s) red[tid] = fmaxf(red[tid], red[tid + s]);
    __syncthreads();
  }
  if (tid == 0) atomicMax(&smax[b], __float_as_uint(red[0]));
}

__global__ void scales_fin(const unsigned int* __restrict__ smax,
                           float* __restrict__ scales) {
  const int i = threadIdx.x;
  if (i < 16) scales[i] = fmaxf(__uint_as_float(smax[i]) / FP8_MAX_C, EPS_C);
}

// ---- prep k_comb[h][t][d] bf16 ----
__global__ void prep_k(const float* __restrict__ k,
                       const float* __restrict__ k_cache,
                       const int* __restrict__ cache_slots,
                       const float* __restrict__ scales,
                       unsigned short* __restrict__ k_comb) {
  const int tid = blockIdx.x * 256 + threadIdx.x;
  const int d8 = tid & 15;
  const int t = (tid >> 4) & (SKV - 1);
  const int h = tid >> 16;
  const int d0 = d8 * 8;
  const float* src;
  float mul;
  if (t < CTX) {
    int slot = cache_slots[t];
    src = k_cache + (size_t)slot * (HKV * D) + h * D + d0;
    mul = scales[h];
  } else {
    src = k + (size_t)(t - CTX) * (HKV * D) + h * D + d0;
    mul = 1.f;
  }
  float4 a = *reinterpret_cast<const float4*>(src);
  float4 bb = *reinterpret_cast<const float4*>(src + 4);
  u16x8 r;
  r[0] = f2bf(a.x * mul);  r[1] = f2bf(a.y * mul);
  r[2] = f2bf(a.z * mul);  r[3] = f2bf(a.w * mul);
  r[4] = f2bf(bb.x * mul); r[5] = f2bf(bb.y * mul);
  r[6] = f2bf(bb.z * mul); r[7] = f2bf(bb.w * mul);
  *reinterpret_cast<u16x8*>(k_comb + ((size_t)h * SKV + t) * D + d0) = r;
}

// ---- prep v_combT[h][d][t] bf16 ----
__global__ void prep_v(const float* __restrict__ v,
                       const float* __restrict__ v_cache,
                       const int* __restrict__ cache_slots,
                       const float* __restrict__ scales,
                       unsigned short* __restrict__ v_combT) {
  const int tid = blockIdx.x * 256 + threadIdx.x;
  const int d = tid & 127;
  const int t8 = (tid >> 7) & 511;
  const int h = tid >> 16;
  const int t0 = t8 * 8;
  const float sc = scales[8 + h];
  u16x8 r;
#pragma unroll
  for (int i = 0; i < 8; ++i) {
    int t = t0 + i;
    float val;
    if (t < CTX) {
      int slot = cache_slots[t];
      val = v_cache[(size_t)slot * (HKV * D) + h * D + d] * sc;
    } else {
      val = v[(size_t)(t - CTX) * (HKV * D) + h * D + d];
    }
    r[i] = f2bf(val);
  }
  *reinterpret_cast<u16x8*>(v_combT + ((size_t)h * D + d) * SKV + t0) = r;
}

#define LDBF(p) (*reinterpret_cast<const bf16x8*>(p))
#define Z4 ((f32x4){0.f, 0.f, 0.f, 0.f})

// Stage 32x128 K tile (8KB) + 128x32 V^T tile (8KB), 256 threads x 2x16B each.
// LDS dest linear; global src pre-swizzled so XOR'd ds_read is conflict-free.
// K: row r=c>>4 (256B rows), col-chunk (c&15)^(r&7).
// V: row d=c>>2 (64B rows),  col-chunk (c&3)^((d>>1)&3)  -> 2-way on read.
#define STAGE(TB, BUFO)                                                        \
  {                                                                            \
    _Pragma("unroll")                                                          \
    for (int j = 0; j < 2; ++j) {                                              \
      const int c = j * 256 + tid;                                             \
      const int r_ = c >> 4;                                                   \
      const int lc_ = (c & 15) ^ (r_ & 7);                                     \
      gld16(kb + (size_t)((TB) + r_) * D + lc_ * 8,                            \
            smem + (BUFO) + c * 16);                                           \
      const int dv_ = c >> 2;                                                  \
      const int cv_ = (c & 3) ^ ((dv_ >> 1) & 3);                              \
      gld16(vb + (size_t)dv_ * SKV + (TB) + cv_ * 8,                           \
            smem + (BUFO) + 8192 + c * 16);                                    \
    }                                                                          \
  }

// exp2 one s-register into float array + accumulate denom
#define EXP4(SREG, P, RSV)                                                     \
  {                                                                            \
    P[0] = __builtin_amdgcn_exp2f(SREG[0] - m);                                \
    P[1] = __builtin_amdgcn_exp2f(SREG[1] - m);                                \
    P[2] = __builtin_amdgcn_exp2f(SREG[2] - m);                                \
    P[3] = __builtin_amdgcn_exp2f(SREG[3] - m);                                \
    RSV += (P[0] + P[1]) + (P[2] + P[3]);                                      \
  }

#define CVTPK(DST, LO, HI)                                                     \
  asm("v_cvt_pk_bf16_f32 %0, %1, %2" : "=v"(DST) : "v"(LO), "v"(HI));
#define SW32(A, B)                                                             \
  asm("v_permlane32_swap_b32 %0, %1" : "+v"(A), "+v"(B));
#define SW16(A, B)                                                             \
  asm("v_permlane16_swap_b32 %0, %1" : "+v"(A), "+v"(B));

// In-register P transpose for a 32-wide P row (kv 0..31) -> one A-fragment.
// (First half of the R10-verified 64-wide PTRANS.)
#define PTRANS32(P0, P1, PF)                                                   \
  {                                                                            \
    unsigned int A_, Ap_, B_, Bp_;                                             \
    CVTPK(A_, P0[0], P0[1]) CVTPK(Ap_, P0[2], P0[3])                           \
    CVTPK(B_, P1[0], P1[1]) CVTPK(Bp_, P1[2], P1[3])                           \
    SW32(A_, B_) SW16(A_, B_)                                                  \
    SW32(Ap_, Bp_) SW16(Ap_, Bp_)                                              \
    union { unsigned int d[4]; bf16x8 v; } u_;                                 \
    u_.d[0] = A_; u_.d[1] = Ap_; u_.d[2] = B_; u_.d[3] = Bp_;                  \
    PF = u_.v;                                                                 \
  }

// QK for one kv-subtile SF (16 rows): 4 shared K-frag reads, 8 MFMAs
#define QKSF(SF, SA, SB)                                                       \
  {                                                                            \
    bf16x8 a0 = LDBF(kc + SF * 4096 + kx0);                                    \
    bf16x8 a1 = LDBF(kc + SF * 4096 + kx1);                                    \
    bf16x8 a2 = LDBF(kc + SF * 4096 + kx2);                                    \
    bf16x8 a3 = LDBF(kc + SF * 4096 + kx3);                                    \
    SA = mfma16(a0, qa0, SA); SA = mfma16(a1, qa1, SA);                        \
    SA = mfma16(a2, qa2, SA); SA = mfma16(a3, qa3, SA);                        \
    SB = mfma16(a0, qb0, SB); SB = mfma16(a1, qb1, SB);                        \
    SB = mfma16(a2, qb2, SB); SB = mfma16(a3, qb3, SB);                        \
  }

// PV for one d-subtile: 1 shared V-frag read feeds both heads (2 MFMAs)
#define PVDT(DT, AA, AB)                                                       \
  {                                                                            \
    bf16x8 va = LDBF(vc + DT * 1024 + vx);                                     \
    AA = mfma16(pfa, va, AA);                                                  \
    AB = mfma16(pfb, va, AB);                                                  \
  }

// ---- flash attention, split-KV xN: 4 waves x (2 heads x 16 q-rows), KVBLK=32.
// grid 256*nsplit; 32KB LDS/block -> 4 blocks/CU, 16 waves/CU at VGPR<=128. ----
__launch_bounds__(256, 4)
__global__ void attn_kernel(const float* __restrict__ q,
                            const unsigned short* __restrict__ k_comb,
                            const unsigned short* __restrict__ v_combT,
                            float* __restrict__ out,     // part-0 partial
                            float* __restrict__ parts,   // parts 1..nsplit-1
                            float* __restrict__ ml,      // [nsplit][SQ][H] (m,l)
                            int nsplit) {
  extern __shared__ __align__(16) char smem[];  // 2 x (8KB K + 8KB V)
  const int bid = blockIdx.x;
  const int hkv = bid & 7;            // XCD-aware
  const int qp_raw = (bid >> 3) & 31;
  const int part = bid >> 8;          // KV part (0..nsplit-1)
  const int qp = (part & 1) ? (31 - qp_raw) : qp_raw;  // balance remap
  const int tid = threadIdx.x;        // 0..255
  const int wid = tid >> 6;
  const int l = tid & 63;
  const int lo = l & 15;
  const int g = l >> 4;
  const int qbase = qp * 32 + (wid >> 1) * 16;
  const int hqa = hkv * 4 + (wid & 1) * 2;   // this wave's heads: hqa, hqa+1
  const int n32 = 97 + qp;                   // total valid 32-tiles (exact)
  const int t0 = (part * n32) / nsplit;
  const int t1 = ((part + 1) * n32) / nsplit;

  const unsigned short* kb = k_comb + (size_t)hkv * SKV * D;
  const unsigned short* vb = v_combT + (size_t)hkv * D * SKV;

  // Q fragments for both heads, pre-scaled by SCALE*log2(e)
  bf16x8 qa0, qa1, qa2, qa3, qb0, qb1, qb2, qb3;
  {
    const float qs = 0.088388347648318447f * 1.4426950408889634f;
    const float* qpA = q + (size_t)(qbase + lo) * (H * D) + hqa * D;
#define QLOAD(PTR, KS, DST)                                                    \
    {                                                                          \
      float4 a = *reinterpret_cast<const float4*>((PTR) + KS * 32 + g * 8);    \
      float4 b = *reinterpret_cast<const float4*>((PTR) + KS * 32 + g * 8 + 4);\
      union { unsigned short u[8]; bf16x8 v; } f;                              \
      f.u[0] = f2bf(a.x * qs); f.u[1] = f2bf(a.y * qs);                        \
      f.u[2] = f2bf(a.z * qs); f.u[3] = f2bf(a.w * qs);                        \
      f.u[4] = f2bf(b.x * qs); f.u[5] = f2bf(b.y * qs);                        \
      f.u[6] = f2bf(b.z * qs); f.u[7] = f2bf(b.w * qs);                        \
      DST = f.v;                                                               \
    }
    QLOAD(qpA, 0, qa0) QLOAD(qpA, 1, qa1) QLOAD(qpA, 2, qa2) QLOAD(qpA, 3, qa3)
    const float* qpB = qpA + D;
    QLOAD(qpB, 0, qb0) QLOAD(qpB, 1, qb1) QLOAD(qpB, 2, qb2) QLOAD(qpB, 3, qb3)
#undef QLOAD
  }

  f32x4 aa0 = Z4, aa1 = Z4, aa2 = Z4, aa3 = Z4;
  f32x4 aa4 = Z4, aa5 = Z4, aa6 = Z4, aa7 = Z4;
  f32x4 ab0 = Z4, ab1 = Z4, ab2 = Z4, ab3 = Z4;
  f32x4 ab4 = Z4, ab5 = Z4, ab6 = Z4, ab7 = Z4;
  float m = -1e30f;            // wave-uniform running max (log2 units)
  float lsa = 0.f, lsb = 0.f;  // per-lane partial denominators (row = lo)

  // K swizzled read offsets (match STAGE's source permutation)
  const int xr = lo & 7;
  const int kx0 = ((0 + g) ^ xr) << 4;
  const int kx1 = ((4 + g) ^ xr) << 4;
  const int kx2 = ((8 + g) ^ xr) << 4;
  const int kx3 = ((12 + g) ^ xr) << 4;
  const int vx = ((g ^ ((lo >> 1) & 3))) << 4;
  const char* kbl = smem + lo * 256;          // + buf*16384 + sf*4096 + kx
  const char* vbl = smem + 8192 + lo * 64;    // + buf*16384 + dt*1024 + vx

  int cur = 0;
  STAGE(t0 * 32, 0)
  stage_sync();

  for (int t = t0; t < t1; ++t) {
    if (t + 1 < t1) STAGE((t + 1) * 32, (cur ^ 1) * 16384)

    const char* kc = kbl + cur * 16384;
    const char* vc = vbl + cur * 16384;

    // ---- swapped QK^T for both heads (shared K-frag reads) ----
    f32x4 sa0 = Z4, sa1 = Z4, sb0 = Z4, sb1 = Z4;
    __builtin_amdgcn_s_setprio(1);
    QKSF(0, sa0, sb0)
    QKSF(1, sa1, sb1)
    __builtin_amdgcn_s_setprio(0);

    // ---- lazy online softmax (shared m; no cross-lane in common path) ----
    float pmax = fmaxf(fmaxf(fmaxf(sa0[0], sa0[1]), fmaxf(sa0[2], sa0[3])),
                       fmaxf(fmaxf(sa1[0], sa1[1]), fmaxf(sa1[2], sa1[3])));
    pmax = fmaxf(pmax,
                 fmaxf(fmaxf(fmaxf(sb0[0], sb0[1]), fmaxf(sb0[2], sb0[3])),
                       fmaxf(fmaxf(sb1[0], sb1[1]), fmaxf(sb1[2], sb1[3]))));
    if (!__all(pmax - m <= 8.f)) {
      float rm = fmaxf(pmax, __shfl_xor(pmax, 16));
      rm = fmaxf(rm, __shfl_xor(rm, 32));
      float mn = fmaxf(m, rm);
      float scl = __builtin_amdgcn_exp2f(m - mn);
      lsa *= scl; lsb *= scl;
      aa0 *= scl; aa1 *= scl; aa2 *= scl; aa3 *= scl;
      aa4 *= scl; aa5 *= scl; aa6 *= scl; aa7 *= scl;
      ab0 *= scl; ab1 *= scl; ab2 *= scl; ab3 *= scl;
      ab4 *= scl; ab5 *= scl; ab6 *= scl; ab7 *= scl;
      m = mn;
    }

    float pa0[4], pa1[4], pb0[4], pb1[4];
    EXP4(sa0, pa0, lsa) EXP4(sa1, pa1, lsa)
    EXP4(sb0, pb0, lsb) EXP4(sb1, pb1, lsb)

    // ---- in-register P transpose (cvt_pk + permlane swaps; no LDS) ----
    bf16x8 pfa, pfb;
    PTRANS32(pa0, pa1, pfa)
    PTRANS32(pb0, pb1, pfb)

    // ---- PV for both heads (shared V-frag reads from LDS) ----
    __builtin_amdgcn_s_setprio(1);
    PVDT(0, aa0, ab0)
    PVDT(1, aa1, ab1)
    PVDT(2, aa2, ab2)
    PVDT(3, aa3, ab3)
    PVDT(4, aa4, ab4)
    PVDT(5, aa5, ab5)
    PVDT(6, aa6, ab6)
    PVDT(7, aa7, ab7)
    __builtin_amdgcn_s_setprio(0);

    stage_sync();
    cur ^= 1;
  }

  // ---- epilogue: store UNNORMALIZED partials + (m, l) per row ----
  lsa += __shfl_xor(lsa, 16); lsa += __shfl_xor(lsa, 32);
  lsb += __shfl_xor(lsb, 16); lsb += __shfl_xor(lsb, 32);
  float* dst = (part == 0) ? out : parts + (size_t)(part - 1) * SQ * H * D;
  if (g == 0) {  // lanes 0..15 cover the wave's 16 q-rows
    float2 v;
    v.x = m; v.y = lsa;
    *reinterpret_cast<float2*>(ml + ((size_t)part * SQ * H + (qbase + lo) * H + hqa) * 2) = v;
    v.y = lsb;
    *reinterpret_cast<float2*>(ml + ((size_t)part * SQ * H + (qbase + lo) * H + hqa + 1) * 2) = v;
  }
#pragma unroll
  for (int r = 0; r < 4; ++r) {
    float* opa = dst + (size_t)(qbase + g * 4 + r) * (H * D) + hqa * D + lo;
    float* opb = opa + D;
    opa[0 * 16] = aa0[r]; opb[0 * 16] = ab0[r];
    opa[1 * 16] = aa1[r]; opb[1 * 16] = ab1[r];
    opa[2 * 16] = aa2[r]; opb[2 * 16] = ab2[r];
    opa[3 * 16] = aa3[r]; opb[3 * 16] = ab3[r];
    opa[4 * 16] = aa4[r]; opb[4 * 16] = ab4[r];
    opa[5 * 16] = aa5[r]; opb[5 * 16] = ab5[r];
    opa[6 * 16] = aa6[r]; opb[6 * 16] = ab6[r];
    opa[7 * 16] = aa7[r]; opb[7 * 16] = ab7[r];
  }
}

// ---- merge nsplit KV-parts: out = sum(O_p*w_p) / sum(l_p*w_p) ----
__global__ void merge_kernel(float* __restrict__ out,
                             const float* __restrict__ parts,
                             const float* __restrict__ ml,
                             int nsplit) {
  const int idx = blockIdx.x * 256 + threadIdx.x;  // < SQ*H*D/4
  const int h = (idx >> 5) & 31;
  const int qrow = idx >> 10;
  const float2* mp = (const float2*)ml;
  float mm = -1e30f;
  for (int p = 0; p < nsplit; ++p)
    mm = fmaxf(mm, mp[p * SQ * H + qrow * H + h].x);
  float den = 0.f;
  float4 num = {0.f, 0.f, 0.f, 0.f};
  for (int p = 0; p < nsplit; ++p) {
    float2 A = mp[p * SQ * H + qrow * H + h];
    float w = __builtin_amdgcn_exp2f(A.x - mm);
    den += A.y * w;
    const float4* src = (p == 0) ? reinterpret_cast<const float4*>(out)
                                 : reinterpret_cast<const float4*>(
                                       parts + (size_t)(p - 1) * SQ * H * D);
    float4 o = src[idx];
    num.x += o.x * w; num.y += o.y * w;
    num.z += o.z * w; num.w += o.w * w;
  }
  float inv = 1.f / den;
  float4 r;
  r.x = num.x * inv; r.y = num.y * inv;
  r.z = num.z * inv; r.w = num.w * inv;
  reinterpret_cast<float4*>(out)[idx] = r;
}

extern "C" void kernel_launch(void* const* d_in, const int* in_sizes, int n_in,
                              void* d_out, int out_size, void* d_ws, size_t ws_size,
                              hipStream_t stream) {
  (void)in_sizes; (void)n_in; (void)out_size;
  const float* q = (const float*)d_in[0];
  const float* k = (const float*)d_in[1];
  const float* v = (const float*)d_in[2];
  const float* k_cache = (const float*)d_in[3];
  const float* v_cache = (const float*)d_in[4];
  const int* cache_slots = (const int*)d_in[6];
  float* out = (float*)d_out;

  const size_t PART_FLOATS = (size_t)SQ * H * D;          // 16 MB as f32
  const size_t PREP = 256 + (size_t)32 * 1024 * 1024 / 2; // smax/scales + 16MB
  // nsplit=4 needs PREP + 3 partials + 1MB ml; fall back to proven nsplit=2.
  const size_t need4 = PREP + 3 * PART_FLOATS * 4 + 4 * (size_t)SQ * H * 8;
  const int nsplit = (ws_size >= need4) ? 4 : 2;

  unsigned int* smax = (unsigned int*)d_ws;                       // 16 u32
  float* scales = (float*)((char*)d_ws + 64);                     // 16 floats
  unsigned short* k_comb = (unsigned short*)((char*)d_ws + 256);  // 8 MB
  unsigned short* v_combT = k_comb + (size_t)HKV * SKV * D;       // 8 MB
  float* parts = (float*)((char*)d_ws + PREP);                    // (nsplit-1)x16MB
  float* ml = parts + (size_t)(nsplit - 1) * PART_FLOATS;

  hipMemsetAsync(smax, 0, 64, stream);
  scales_part<<<128, 256, 0, stream>>>(k, v, smax);
  scales_fin<<<1, 64, 0, stream>>>(smax, scales);
  prep_k<<<2048, 256, 0, stream>>>(k, k_cache, cache_slots, scales, k_comb);
  prep_v<<<2048, 256, 0, stream>>>(v, v_cache, cache_slots, scales, v_combT);
  attn_kernel<<<256 * nsplit, 256, 32768, stream>>>(q, k_comb, v_combT, out,
                                                    parts, ml, nsplit);
  merge_kernel<<<4096, 256, 0, stream>>>(out, parts, ml, nsplit);
}

// Round 13
// 111.957 us; speedup vs baseline: 1.9436x; 1.9436x over previous
//
#include <hip/hip_runtime.h>
#include <stdint.h>

#define H 32
#define HKV 8
#define D 128
#define SQ 1024
#define CTX 3072
#define SKV 4096
#define FP8_MAX_C 448.0f
#define EPS_C 1e-8f

typedef __attribute__((ext_vector_type(4))) float f32x4;
typedef __attribute__((ext_vector_type(8))) __bf16 bf16x8;
typedef __attribute__((ext_vector_type(8))) unsigned short u16x8;

__device__ __forceinline__ unsigned short f2bf(float x) {
  unsigned int u = __builtin_bit_cast(unsigned int, x);
  u += 0x7fffu + ((u >> 16) & 1u);
  return (unsigned short)(u >> 16);
}

__device__ __forceinline__ f32x4 mfma16(bf16x8 a, bf16x8 b, f32x4 c) {
  return __builtin_amdgcn_mfma_f32_16x16x32_bf16(a, b, c, 0, 0, 0);
}

// async global->LDS, 16B per lane; dest = wave-uniform base + lane*16
__device__ __forceinline__ void gld16(const unsigned short* g, char* l) {
  __builtin_amdgcn_global_load_lds(
      (const __attribute__((address_space(1))) unsigned int*)g,
      (__attribute__((address_space(3))) unsigned int*)l, 16, 0, 0);
}

// explicit DMA drain before barrier (fixes replay-only race, R6/R7)
__device__ __forceinline__ void stage_sync() {
  asm volatile("s_waitcnt vmcnt(0)" ::: "memory");
  __builtin_amdgcn_sched_barrier(0);
  __syncthreads();
}

// ---- scales stage 1: partial absmax -> atomicMax on float bits ----
__global__ void scales_part(const float* __restrict__ k,
                            const float* __restrict__ v,
                            unsigned int* __restrict__ smax) {
  const int b = blockIdx.x & 15;
  const int part = blockIdx.x >> 4;
  const float* src = (b < HKV) ? k : v;
  const int h = b & 7;
  const int tid = threadIdx.x;
  const int d0 = (tid & 31) * 4;
  float mx = 0.f;
  const int t1 = part * 128 + 128;
  for (int t = part * 128 + (tid >> 5); t < t1; t += 8) {
    float4 vv = *reinterpret_cast<const float4*>(src + (size_t)t * (HKV * D) + h * D + d0);
    mx = fmaxf(mx, fmaxf(fmaxf(fabsf(vv.x), fabsf(vv.y)),
                         fmaxf(fabsf(vv.z), fabsf(vv.w))));
  }
  __shared__ float red[256];
  red[tid] = mx;
  __syncthreads();
  for (int s = 128; s > 0; s >>= 1) {
    if (tid < s) red[tid] = fmaxf(red[tid], red[tid + s]);
    __syncthreads();
  }
  if (tid == 0) atomicMax(&smax[b], __float_as_uint(red[0]));
}

__global__ void scales_fin(const unsigned int* __restrict__ smax,
                           float* __restrict__ scales) {
  const int i = threadIdx.x;
  if (i < 16) scales[i] = fmaxf(__uint_as_float(smax[i]) / FP8_MAX_C, EPS_C);
}

// ---- fused prep: blocks 0..2047 build k_comb[h][t][d]; 2048..4095 build
//      v_combT[h][d][t] (transposed). Same code paths as the R10 pair. ----
__global__ void prep_kv(const float* __restrict__ k,
                        const float* __restrict__ v,
                        const float* __restrict__ k_cache,
                        const float* __restrict__ v_cache,
                        const int* __restrict__ cache_slots,
                        const float* __restrict__ scales,
                        unsigned short* __restrict__ k_comb,
                        unsigned short* __restrict__ v_combT) {
  if (blockIdx.x < 2048) {
    const int tid = blockIdx.x * 256 + threadIdx.x;
    const int d8 = tid & 15;
    const int t = (tid >> 4) & (SKV - 1);
    const int h = tid >> 16;
    const int d0 = d8 * 8;
    const float* src;
    float mul;
    if (t < CTX) {
      int slot = cache_slots[t];
      src = k_cache + (size_t)slot * (HKV * D) + h * D + d0;
      mul = scales[h];
    } else {
      src = k + (size_t)(t - CTX) * (HKV * D) + h * D + d0;
      mul = 1.f;
    }
    float4 a = *reinterpret_cast<const float4*>(src);
    float4 bb = *reinterpret_cast<const float4*>(src + 4);
    u16x8 r;
    r[0] = f2bf(a.x * mul);  r[1] = f2bf(a.y * mul);
    r[2] = f2bf(a.z * mul);  r[3] = f2bf(a.w * mul);
    r[4] = f2bf(bb.x * mul); r[5] = f2bf(bb.y * mul);
    r[6] = f2bf(bb.z * mul); r[7] = f2bf(bb.w * mul);
    *reinterpret_cast<u16x8*>(k_comb + ((size_t)h * SKV + t) * D + d0) = r;
  } else {
    const int tid = (blockIdx.x - 2048) * 256 + threadIdx.x;
    const int d = tid & 127;
    const int t8 = (tid >> 7) & 511;
    const int h = tid >> 16;
    const int t0 = t8 * 8;
    const float sc = scales[8 + h];
    u16x8 r;
#pragma unroll
    for (int i = 0; i < 8; ++i) {
      int t = t0 + i;
      float val;
      if (t < CTX) {
        int slot = cache_slots[t];
        val = v_cache[(size_t)slot * (HKV * D) + h * D + d] * sc;
      } else {
        val = v[(size_t)(t - CTX) * (HKV * D) + h * D + d];
      }
      r[i] = f2bf(val);
    }
    *reinterpret_cast<u16x8*>(v_combT + ((size_t)h * D + d) * SKV + t0) = r;
  }
}

#define LDBF(p) (*reinterpret_cast<const bf16x8*>(p))
#define Z4 ((f32x4){0.f, 0.f, 0.f, 0.f})

// Stage 64x128 K tile (16KB) + 128x64 V^T tile (16KB), 256 threads.
// LDS dest linear; global src pre-swizzled so XOR'd ds_read is conflict-free.
#define STAGE(TB, BUFO)                                                        \
  {                                                                            \
    _Pragma("unroll")                                                          \
    for (int j = 0; j < 4; ++j) {                                              \
      const int c = wid * 256 + j * 64 + l;                                    \
      const int r_ = c >> 4;                                                   \
      const int lc_ = (c & 15) ^ (r_ & 7);                                     \
      gld16(kb + (size_t)((TB) + r_) * D + lc_ * 8,                            \
            smem + (BUFO) + c * 16);                                           \
      const int dv_ = c >> 3;                                                  \
      const int lv_ = (c & 7) ^ (dv_ & 7);                                     \
      gld16(vb + (size_t)dv_ * SKV + (TB) + lv_ * 8,                           \
            smem + (BUFO) + 16384 + c * 16);                                   \
    }                                                                          \
  }

// exp2 one s-register into float array + accumulate denom
#define EXP4(SREG, P, RSV)                                                     \
  {                                                                            \
    P[0] = __builtin_amdgcn_exp2f(SREG[0] - m);                                \
    P[1] = __builtin_amdgcn_exp2f(SREG[1] - m);                                \
    P[2] = __builtin_amdgcn_exp2f(SREG[2] - m);                                \
    P[3] = __builtin_amdgcn_exp2f(SREG[3] - m);                                \
    RSV += (P[0] + P[1]) + (P[2] + P[3]);                                      \
  }

#define CVTPK(DST, LO, HI)                                                     \
  asm("v_cvt_pk_bf16_f32 %0, %1, %2" : "=v"(DST) : "v"(LO), "v"(HI));
#define SW32(A, B)                                                             \
  asm("v_permlane32_swap_b32 %0, %1" : "+v"(A), "+v"(B));
#define SW16(A, B)                                                             \
  asm("v_permlane16_swap_b32 %0, %1" : "+v"(A), "+v"(B));

// In-register P transpose: C-layout rows -> A-fragment k-slices (R10-verified)
#define PTRANS(P0, P1, P2, P3, PF0, PF1)                                       \
  {                                                                            \
    unsigned int A_, Ap_, B_, Bp_, C_, Cp_, Dd_, Dp_;                          \
    CVTPK(A_, P0[0], P0[1]) CVTPK(Ap_, P0[2], P0[3])                           \
    CVTPK(B_, P1[0], P1[1]) CVTPK(Bp_, P1[2], P1[3])                           \
    CVTPK(C_, P2[0], P2[1]) CVTPK(Cp_, P2[2], P2[3])                           \
    CVTPK(Dd_, P3[0], P3[1]) CVTPK(Dp_, P3[2], P3[3])                          \
    SW32(A_, B_) SW16(A_, B_)                                                  \
    SW32(Ap_, Bp_) SW16(Ap_, Bp_)                                              \
    SW32(C_, Dd_) SW16(C_, Dd_)                                                \
    SW32(Cp_, Dp_) SW16(Cp_, Dp_)                                              \
    union { unsigned int d[4]; bf16x8 v; } u0_, u1_;                           \
    u0_.d[0] = A_; u0_.d[1] = Ap_; u0_.d[2] = B_; u0_.d[3] = Bp_;              \
    u1_.d[0] = C_; u1_.d[1] = Cp_; u1_.d[2] = Dd_; u1_.d[3] = Dp_;             \
    PF0 = u0_.v; PF1 = u1_.v;                                                  \
  }

// QK for one kv-subtile SF: 4 shared K-frag reads feed both heads (8 MFMAs)
#define QKSF(SF, SA, SB)                                                       \
  {                                                                            \
    bf16x8 a0 = LDBF(kc + SF * 4096 + kx0);                                    \
    bf16x8 a1 = LDBF(kc + SF * 4096 + kx1);                                    \
    bf16x8 a2 = LDBF(kc + SF * 4096 + kx2);                                    \
    bf16x8 a3 = LDBF(kc + SF * 4096 + kx3);                                    \
    SA = mfma16(a0, qa0, SA); SA = mfma16(a1, qa1, SA);                        \
    SA = mfma16(a2, qa2, SA); SA = mfma16(a3, qa3, SA);                        \
    SB = mfma16(a0, qb0, SB); SB = mfma16(a1, qb1, SB);                        \
    SB = mfma16(a2, qb2, SB); SB = mfma16(a3, qb3, SB);                        \
  }

// PV for one d-subtile DT: 2 shared V-frag reads feed both heads (4 MFMAs)
#define PVDT(DT, AA, AB)                                                       \
  {                                                                            \
    bf16x8 va = LDBF(vc + DT * 2048 + vxa);                                    \
    bf16x8 vw = LDBF(vc + DT * 2048 + vxb);                                    \
    AA = mfma16(pfa0, va, AA); AA = mfma16(pfa1, vw, AA);                      \
    AB = mfma16(pfb0, va, AB); AB = mfma16(pfb1, vw, AB);                      \
  }

// ---- flash attention, split-KV: 4 waves x (2 heads x 16 q-rows), KVBLK=64 ----
// grid 512 = 8 hkv x 32 q-pairs x 2 kv-halves; partial (unnormalized) output.
__launch_bounds__(256, 2)
__global__ void attn_kernel(const float* __restrict__ q,
                            const unsigned short* __restrict__ k_comb,
                            const unsigned short* __restrict__ v_combT,
                            float* __restrict__ out,     // half-0 partial
                            float* __restrict__ part1,   // half-1 partial
                            float* __restrict__ ml) {    // [2][SQ][H] (m,l)
  extern __shared__ __align__(16) char smem[];  // 2 x { K 16KB | V 16KB }
  const int bid = blockIdx.x;
  const int hkv = bid & 7;            // XCD-aware
  const int qp_raw = (bid >> 3) & 31;
  const int half = bid >> 8;          // KV half
  const int qp = half ? (31 - qp_raw) : qp_raw;  // balance remap
  const int tid = threadIdx.x;        // 0..255
  const int wid = tid >> 6;
  const int l = tid & 63;
  const int lo = l & 15;
  const int g = l >> 4;
  const int qbase = qp * 32 + (wid >> 1) * 16;
  const int hqa = hkv * 4 + (wid & 1) * 2;   // this wave's heads: hqa, hqa+1
  const int nt32 = 97 + qp;
  const int n64 = (nt32 + 1) >> 1;
  const int nh = (n64 + 1) >> 1;
  const int t0 = half ? nh : 0;
  const int t1 = half ? n64 : nh;
  const bool tail = (nt32 & 1) && half;      // mask upper 32 at t==n64-1

  const unsigned short* kb = k_comb + (size_t)hkv * SKV * D;
  const unsigned short* vb = v_combT + (size_t)hkv * D * SKV;

  // Q fragments for both heads, pre-scaled by SCALE*log2(e)
  bf16x8 qa0, qa1, qa2, qa3, qb0, qb1, qb2, qb3;
  {
    const float qs = 0.088388347648318447f * 1.4426950408889634f;
    const float* qpA = q + (size_t)(qbase + lo) * (H * D) + hqa * D;
#define QLOAD(PTR, KS, DST)                                                    \
    {                                                                          \
      float4 a = *reinterpret_cast<const float4*>((PTR) + KS * 32 + g * 8);    \
      float4 b = *reinterpret_cast<const float4*>((PTR) + KS * 32 + g * 8 + 4);\
      union { unsigned short u[8]; bf16x8 v; } f;                              \
      f.u[0] = f2bf(a.x * qs); f.u[1] = f2bf(a.y * qs);                        \
      f.u[2] = f2bf(a.z * qs); f.u[3] = f2bf(a.w * qs);                        \
      f.u[4] = f2bf(b.x * qs); f.u[5] = f2bf(b.y * qs);                        \
      f.u[6] = f2bf(b.z * qs); f.u[7] = f2bf(b.w * qs);                        \
      DST = f.v;                                                               \
    }
    QLOAD(qpA, 0, qa0) QLOAD(qpA, 1, qa1) QLOAD(qpA, 2, qa2) QLOAD(qpA, 3, qa3)
    const float* qpB = qpA + D;
    QLOAD(qpB, 0, qb0) QLOAD(qpB, 1, qb1) QLOAD(qpB, 2, qb2) QLOAD(qpB, 3, qb3)
#undef QLOAD
  }

  f32x4 aa0 = Z4, aa1 = Z4, aa2 = Z4, aa3 = Z4;
  f32x4 aa4 = Z4, aa5 = Z4, aa6 = Z4, aa7 = Z4;
  f32x4 ab0 = Z4, ab1 = Z4, ab2 = Z4, ab3 = Z4;
  f32x4 ab4 = Z4, ab5 = Z4, ab6 = Z4, ab7 = Z4;
  float m = -1e30f;            // wave-uniform running max (log2 units)
  float lsa = 0.f, lsb = 0.f;  // per-lane partial denominators (row = lo)

  // K/V swizzled read offsets (match STAGE's source permutation)
  const int xr = lo & 7;
  const int kx0 = ((0 + g) ^ xr) << 4;
  const int kx1 = ((4 + g) ^ xr) << 4;
  const int kx2 = ((8 + g) ^ xr) << 4;
  const int kx3 = ((12 + g) ^ xr) << 4;
  const int vxa = ((g) ^ xr) << 4;
  const int vxb = ((g + 4) ^ xr) << 4;
  const char* kbl = smem + lo * 256;           // + buf*32768 + sf*4096 + kx
  const char* vbl = smem + 16384 + lo * 128;   // + buf*32768 + dt*2048 + vx

  int cur = 0;
  STAGE(t0 * 64, 0)
  stage_sync();

  for (int t = t0; t < t1; ++t) {
    if (t + 1 < t1) STAGE((t + 1) * 64, (cur ^ 1) * 32768)

    const char* kc = kbl + cur * 32768;
    const char* vc = vbl + cur * 32768;

    // ---- swapped QK^T for both heads (shared K-frag reads) ----
    f32x4 sa0 = Z4, sa1 = Z4, sa2 = Z4, sa3 = Z4;
    f32x4 sb0 = Z4, sb1 = Z4, sb2 = Z4, sb3 = Z4;
    __builtin_amdgcn_s_setprio(1);
    QKSF(0, sa0, sb0)
    QKSF(1, sa1, sb1)
    QKSF(2, sa2, sb2)
    QKSF(3, sa3, sb3)
    __builtin_amdgcn_s_setprio(0);

    if (tail && t == n64 - 1) {
      sa2 = (f32x4){-1e30f, -1e30f, -1e30f, -1e30f};
      sa3 = (f32x4){-1e30f, -1e30f, -1e30f, -1e30f};
      sb2 = (f32x4){-1e30f, -1e30f, -1e30f, -1e30f};
      sb3 = (f32x4){-1e30f, -1e30f, -1e30f, -1e30f};
    }

    // ---- lazy online softmax (shared m; no cross-lane in common path) ----
    float pmax = fmaxf(fmaxf(fmaxf(sa0[0], sa0[1]), fmaxf(sa0[2], sa0[3])),
                       fmaxf(fmaxf(sa1[0], sa1[1]), fmaxf(sa1[2], sa1[3])));
    pmax = fmaxf(pmax,
                 fmaxf(fmaxf(fmaxf(sa2[0], sa2[1]), fmaxf(sa2[2], sa2[3])),
                       fmaxf(fmaxf(sa3[0], sa3[1]), fmaxf(sa3[2], sa3[3]))));
    pmax = fmaxf(pmax,
                 fmaxf(fmaxf(fmaxf(sb0[0], sb0[1]), fmaxf(sb0[2], sb0[3])),
                       fmaxf(fmaxf(sb1[0], sb1[1]), fmaxf(sb1[2], sb1[3]))));
    pmax = fmaxf(pmax,
                 fmaxf(fmaxf(fmaxf(sb2[0], sb2[1]), fmaxf(sb2[2], sb2[3])),
                       fmaxf(fmaxf(sb3[0], sb3[1]), fmaxf(sb3[2], sb3[3]))));
    if (!__all(pmax - m <= 8.f)) {
      float rm = fmaxf(pmax, __shfl_xor(pmax, 16));
      rm = fmaxf(rm, __shfl_xor(rm, 32));
      float mn = fmaxf(m, rm);
      float scl = __builtin_amdgcn_exp2f(m - mn);
      lsa *= scl; lsb *= scl;
      aa0 *= scl; aa1 *= scl; aa2 *= scl; aa3 *= scl;
      aa4 *= scl; aa5 *= scl; aa6 *= scl; aa7 *= scl;
      ab0 *= scl; ab1 *= scl; ab2 *= scl; ab3 *= scl;
      ab4 *= scl; ab5 *= scl; ab6 *= scl; ab7 *= scl;
      m = mn;
    }

    float pa0[4], pa1[4], pa2[4], pa3[4], pb0[4], pb1[4], pb2[4], pb3[4];
    EXP4(sa0, pa0, lsa) EXP4(sa1, pa1, lsa) EXP4(sa2, pa2, lsa) EXP4(sa3, pa3, lsa)
    EXP4(sb0, pb0, lsb) EXP4(sb1, pb1, lsb) EXP4(sb2, pb2, lsb) EXP4(sb3, pb3, lsb)

    // ---- in-register P transpose (cvt_pk + permlane swaps; no LDS) ----
    bf16x8 pfa0, pfa1, pfb0, pfb1;
    PTRANS(pa0, pa1, pa2, pa3, pfa0, pfa1)
    PTRANS(pb0, pb1, pb2, pb3, pfb0, pfb1)

    // ---- PV for both heads (shared V-frag reads) ----
    __builtin_amdgcn_s_setprio(1);
    PVDT(0, aa0, ab0)
    PVDT(1, aa1, ab1)
    PVDT(2, aa2, ab2)
    PVDT(3, aa3, ab3)
    PVDT(4, aa4, ab4)
    PVDT(5, aa5, ab5)
    PVDT(6, aa6, ab6)
    PVDT(7, aa7, ab7)
    __builtin_amdgcn_s_setprio(0);

    stage_sync();
    cur ^= 1;
  }

  // ---- epilogue: store UNNORMALIZED partials + (m, l) per row ----
  lsa += __shfl_xor(lsa, 16); lsa += __shfl_xor(lsa, 32);
  lsb += __shfl_xor(lsb, 16); lsb += __shfl_xor(lsb, 32);
  float* dst = half ? part1 : out;
  if (g == 0) {  // lanes 0..15 cover the wave's 16 q-rows
    float2 v;
    v.x = m; v.y = lsa;
    *reinterpret_cast<float2*>(ml + ((size_t)half * SQ * H + (qbase + lo) * H + hqa) * 2) = v;
    v.y = lsb;
    *reinterpret_cast<float2*>(ml + ((size_t)half * SQ * H + (qbase + lo) * H + hqa + 1) * 2) = v;
  }
#pragma unroll
  for (int r = 0; r < 4; ++r) {
    float* opa = dst + (size_t)(qbase + g * 4 + r) * (H * D) + hqa * D + lo;
    float* opb = opa + D;
    opa[0 * 16] = aa0[r]; opb[0 * 16] = ab0[r];
    opa[1 * 16] = aa1[r]; opb[1 * 16] = ab1[r];
    opa[2 * 16] = aa2[r]; opb[2 * 16] = ab2[r];
    opa[3 * 16] = aa3[r]; opb[3 * 16] = ab3[r];
    opa[4 * 16] = aa4[r]; opb[4 * 16] = ab4[r];
    opa[5 * 16] = aa5[r]; opb[5 * 16] = ab5[r];
    opa[6 * 16] = aa6[r]; opb[6 * 16] = ab6[r];
    opa[7 * 16] = aa7[r]; opb[7 * 16] = ab7[r];
  }
}

// ---- merge the two KV-halves: out = (Oa*wa + Ob*wb) / (la*wa + lb*wb) ----
__global__ void merge_kernel(float* __restrict__ out,
                             const float* __restrict__ part1,
                             const float* __restrict__ ml) {
  const int idx = blockIdx.x * 256 + threadIdx.x;  // < SQ*H*D/4
  const int h = (idx >> 5) & 31;
  const int qrow = idx >> 10;
  const float2* mp = (const float2*)ml;
  float2 A = mp[qrow * H + h];
  float2 B = mp[SQ * H + qrow * H + h];
  float mm = fmaxf(A.x, B.x);
  float wa = __builtin_amdgcn_exp2f(A.x - mm);
  float wb = __builtin_amdgcn_exp2f(B.x - mm);
  float inv = 1.f / (A.y * wa + B.y * wb);
  float4 oa = reinterpret_cast<float4*>(out)[idx];
  float4 ob = reinterpret_cast<const float4*>(part1)[idx];
  float4 r;
  r.x = (oa.x * wa + ob.x * wb) * inv;
  r.y = (oa.y * wa + ob.y * wb) * inv;
  r.z = (oa.z * wa + ob.z * wb) * inv;
  r.w = (oa.w * wa + ob.w * wb) * inv;
  reinterpret_cast<float4*>(out)[idx] = r;
}

extern "C" void kernel_launch(void* const* d_in, const int* in_sizes, int n_in,
                              void* d_out, int out_size, void* d_ws, size_t ws_size,
                              hipStream_t stream) {
  (void)in_sizes; (void)n_in; (void)out_size; (void)ws_size;
  const float* q = (const float*)d_in[0];
  const float* k = (const float*)d_in[1];
  const float* v = (const float*)d_in[2];
  const float* k_cache = (const float*)d_in[3];
  const float* v_cache = (const float*)d_in[4];
  const int* cache_slots = (const int*)d_in[6];
  float* out = (float*)d_out;

  unsigned int* smax = (unsigned int*)d_ws;                       // 16 u32
  float* scales = (float*)((char*)d_ws + 64);                     // 16 floats
  unsigned short* k_comb = (unsigned short*)((char*)d_ws + 256);  // 8 MB
  unsigned short* v_combT = k_comb + (size_t)HKV * SKV * D;       // 8 MB
  float* part1 = (float*)((char*)d_ws + 256 + (size_t)32 * 1024 * 1024 / 2); // 16 MB
  float* ml = part1 + (size_t)SQ * H * D;                         // 512 KB

  hipMemsetAsync(smax, 0, 64, stream);
  scales_part<<<128, 256, 0, stream>>>(k, v, smax);
  scales_fin<<<1, 64, 0, stream>>>(smax, scales);
  prep_kv<<<4096, 256, 0, stream>>>(k, v, k_cache, v_cache, cache_slots,
                                    scales, k_comb, v_combT);
  attn_kernel<<<512, 256, 65536, stream>>>(q, k_comb, v_combT, out, part1, ml);
  merge_kernel<<<4096, 256, 0, stream>>>(out, part1, ml);
}